// Round 9
// baseline (561.049 us; speedup 1.0000x reference)
//
#include <hip/hip_runtime.h>

#define B_    32
#define CIN_  96
#define EXC_  102
#define INH_  26
#define HH    64
#define WW    64
#define HW_   4096
#define NPOS  (B_*HW_)   // 131072
#define NPART 512        // partial buffers per scatter
#define NEE   (EXC_*CIN_ + EXC_)      // 9894: yx_ee + yu_e
#define NIE   (EXC_*INH_)             // 2652
#define N1U   (EXC_*CIN_*25)          // 244800
#define N2U   (INH_*EXC_*25)          // 66300
#define N3U   (EXC_*INH_*25)          // 66300

typedef short bf8 __attribute__((ext_vector_type(8)));
typedef float f32x4 __attribute__((ext_vector_type(4)));

__device__ __forceinline__ int refl(int i) {
    if (i < 0) i = -i;
    if (i > 63) i = 126 - i;
    return i;
}

__device__ __forceinline__ short f2bf(float f) {
    unsigned u = __float_as_uint(f);
    return (short)((u + 0x7fffu + ((u >> 16) & 1u)) >> 16);
}

// ---------------------------------------------------------------------------
// Fused front-end: pack all 3 weight tensors + pack x to NHWC bf16 + zero the
// small atomic-target region.
// ---------------------------------------------------------------------------
__global__ __launch_bounds__(256) void pack_all(
    const float* __restrict__ w_ee, const float* __restrict__ w_ei,
    const float* __restrict__ w_ie, const float* __restrict__ x,
    short* __restrict__ wdst, short* __restrict__ xdst,
    float* __restrict__ zreg)
{
    const int blk = blockIdx.x;
    if (blk < 1800) {
        int gi = blk*256 + threadIdx.x;
        if (gi >= 460800) return;
        const float* src; int N, C, NPAD, CPAD; int idx;
        if (gi < 268800)      { src = w_ee; N = 102; C = 96;  NPAD = 112; CPAD = 96;  idx = gi; }
        else if (gi < 371200) { src = w_ei; N = 26;  C = 102; NPAD = 32;  CPAD = 128; idx = gi - 268800; }
        else                  { src = w_ie; N = 102; C = 26;  NPAD = 112; CPAD = 32;  idx = gi - 371200; }
        int tap = idx / (NPAD*CPAD);
        int rem = idx - tap*(NPAD*CPAD);
        int n = rem / CPAD, c = rem - n*CPAD;
        float f = (n < N && c < C) ? src[((size_t)n*C + c)*25 + tap] : 0.f;
        wdst[gi] = f2bf(f);
    } else if (blk < 3848) {
        int bb = blk - 1800;
        int b = bb >> 6, bx = bb & 63;
        const int pos = bx*64 + (threadIdx.x & 63);
        const int cg0 = threadIdx.x >> 6;
        for (int cg = cg0; cg < 96/8; cg += 4) {
            bf8 v;
#pragma unroll
            for (int j = 0; j < 8; ++j)
                v[j] = f2bf(x[((size_t)b*CIN_ + cg*8 + j)*HW_ + pos]);
            *(bf8*)(&xdst[((size_t)b*HW_ + pos)*96 + cg*8]) = v;
        }
    } else {
        for (int i = threadIdx.x; i < INH_*EXC_ + INH_ + 3; i += 256) zreg[i] = 0.f;
    }
}

// NCHW fp32 -> NHWC bf16 pack (fallback path only)
template<int C, int CPAD>
__global__ __launch_bounds__(256) void pack_nhwc(
    const float* __restrict__ src, short* __restrict__ dst)
{
    const int b = blockIdx.z;
    const int pos = blockIdx.x*64 + (threadIdx.x & 63);
    const int cg0 = threadIdx.x >> 6;
    for (int cg = cg0; cg < CPAD/8; cg += 4) {
        bf8 v;
#pragma unroll
        for (int j = 0; j < 8; ++j) {
            int c = cg*8 + j;
            float f = (c < C) ? src[((size_t)b*C + c)*HW_ + pos] : 0.f;
            v[j] = f2bf(f);
        }
        *(bf8*)(&dst[((size_t)b*HW_ + pos)*CPAD + cg*8]) = v;
    }
}

// ---------------------------------------------------------------------------
// MFMA implicit-GEMM 5x5 conv, reflect pad. Block = 16x16 spatial tile,
// 256 thr = 4 waves; wave = 4 Mtiles(rows) x NT Ntiles(16 ch each).
// (R4 lesson: 4 Mtiles/wave required to amortize B-fragment loads.)
// ---------------------------------------------------------------------------
template<int CPAD, int NPAD, int NT, int COUT, int NCHUNK,
         bool RELU, bool ADDIN, bool WFLOAT, int OCPAD, bool WTA>
__global__ __launch_bounds__(256, 2) void conv_mfma(
    const short* __restrict__ src, const short* __restrict__ wgt,
    const float* __restrict__ addin, float* __restrict__ out,
    short* __restrict__ nhwc_out, int* __restrict__ win,
    float* __restrict__ val)
{
    __shared__ __align__(16) short sA[400*40];
    const int t  = threadIdx.x;
    const int bx = blockIdx.x;
    const int b  = blockIdx.z;
    const int h0 = (bx >> 2) * 16;
    const int w0 = (bx &  3) * 16;
    const int lane = t & 63;
    const int wv = t >> 6;
    const int nh = lane & 15;
    const int q  = lane >> 4;

    int goff[7], loff[7];
#pragma unroll
    for (int s = 0; s < 7; ++s) {
        int i = t + 256*s;
        if (i < 1600) {
            int rec = i >> 2, seg = i & 3;
            int lh = rec / 20, lw = rec - lh*20;
            int gh = refl(h0 - 2 + lh), gw = refl(w0 - 2 + lw);
            goff[s] = (b*HW_ + gh*WW + gw) * CPAD + seg*8;
            loff[s] = rec*40 + seg*8;
        } else { goff[s] = 0; loff[s] = -1; }
    }

    f32x4 acc[4][NT];
#pragma unroll
    for (int mt = 0; mt < 4; ++mt)
#pragma unroll
        for (int nt = 0; nt < NT; ++nt) {
            f32x4 z = {0.f, 0.f, 0.f, 0.f};
            acc[mt][nt] = z;
        }

    int abase[4];
#pragma unroll
    for (int mt = 0; mt < 4; ++mt)
        abase[mt] = ((wv*4 + mt)*20 + nh)*40 + q*8;

    for (int ck = 0; ck < NCHUNK; ++ck) {
        const int c0 = ck*32;
        __syncthreads();
#pragma unroll
        for (int s = 0; s < 7; ++s)
            if (loff[s] >= 0)
                *(bf8*)(&sA[loff[s]]) = *(const bf8*)(&src[goff[s] + c0]);
        __syncthreads();
        const short* wch = wgt + c0 + nh*CPAD + q*8;
        for (int dh = 0; dh < 5; ++dh) {
#pragma unroll
            for (int dw = 0; dw < 5; ++dw) {
                const int tap = dh*5 + dw;
                bf8 bfr[NT];
#pragma unroll
                for (int nt = 0; nt < NT; ++nt)
                    bfr[nt] = *(const bf8*)(&wch[(size_t)(tap*NPAD + nt*16)*CPAD]);
                bf8 afr[4];
#pragma unroll
                for (int mt = 0; mt < 4; ++mt)
                    afr[mt] = *(const bf8*)(&sA[abase[mt] + (dh*20 + dw)*40]);
#pragma unroll
                for (int mt = 0; mt < 4; ++mt)
#pragma unroll
                    for (int nt = 0; nt < NT; ++nt)
                        acc[mt][nt] = __builtin_amdgcn_mfma_f32_16x16x32_bf16(
                            afr[mt], bfr[nt], acc[mt][nt], 0, 0, 0);
            }
        }
    }

    // epilogue: D row (q*4+reg) = position col, D col (nh) = channel
#pragma unroll
    for (int mt = 0; mt < 4; ++mt) {
        const int rowi = h0 + wv*4 + mt;
#pragma unroll
        for (int nt = 0; nt < NT; ++nt) {
            const int chn = nt*16 + nh;
            if (WFLOAT && chn < COUT) {
                size_t obase = ((size_t)(b*COUT + chn))*HW_ + rowi*WW + w0 + q*4;
#pragma unroll
                for (int r = 0; r < 4; ++r) {
                    float v = acc[mt][nt][r];
                    if (RELU) v = fmaxf(v, 0.f);
                    if (ADDIN) v += addin[obase + r];
                    out[obase + r] = v;
                }
            }
            if (OCPAD > 0) {
#pragma unroll
                for (int r = 0; r < 4; ++r) {
                    float v = acc[mt][nt][r];
                    if (RELU) v = fmaxf(v, 0.f);
                    int pos = rowi*WW + w0 + q*4 + r;
                    nhwc_out[((size_t)b*HW_ + pos)*OCPAD + chn] = f2bf(v);
                }
            }
        }
        if (OCPAD > NT*16) {
#pragma unroll
            for (int r = 0; r < 4; ++r) {
                int pos = rowi*WW + w0 + q*4 + r;
                for (int ct = NT*16 + nh; ct < OCPAD; ct += 16)
                    nhwc_out[((size_t)b*HW_ + pos)*OCPAD + ct] = 0;
            }
        }
        if (WTA) {
#pragma unroll
            for (int r = 0; r < 4; ++r) {
                float bv = -3.402823e38f; int bc = 0;
#pragma unroll
                for (int nt = 0; nt < NT; ++nt) {
                    const int chn = nt*16 + nh;
                    float v = acc[mt][nt][r];
                    if (RELU) v = fmaxf(v, 0.f);
                    if (chn < COUT && v > bv) { bv = v; bc = chn; }
                }
#pragma unroll
                for (int off = 1; off < 16; off <<= 1) {
                    float ov = __shfl_xor(bv, off);
                    int   oc = __shfl_xor(bc, off);
                    if (ov > bv || (ov == bv && oc < bc)) { bv = ov; bc = oc; }
                }
                if (nh == 0) {
                    int p = b*HW_ + rowi*WW + w0 + q*4 + r;
                    win[p] = bc; val[p] = bv;
                }
            }
        }
    }
}

// Depthwise 5x5 surround-modulation conv, ZERO padding. 32x32 tile, TW=4.
__global__ __launch_bounds__(256) void smconv_v2(
    const float* __restrict__ in, const float* __restrict__ sm,
    float* __restrict__ out)
{
    __shared__ __align__(16) float sx[36*36];
    const int tid = threadIdx.x;
    const int tile = blockIdx.x;
    const int e = blockIdx.y;
    const int b = blockIdx.z;
    const int h0 = (tile >> 1) * 32, w0 = (tile & 1) * 32;
    const int r  = tid >> 3;
    const int cg = (tid & 7) * 4;
    const float* inc = in + ((size_t)(b*EXC_ + e))*HW_;
#pragma unroll
    for (int it = 0; it < 6; ++it) {
        int i = tid + it*256;
        if (i < 1296) {
            int lh = i / 36, lw = i - lh*36;
            int gh = h0 - 2 + lh, gw = w0 - 2 + lw;
            float v = 0.f;
            if (gh >= 0 && gh < HH && gw >= 0 && gw < WW) v = inc[gh*WW + gw];
            sx[i] = v;
        }
    }
    __syncthreads();
    float a0 = 0.f, a1 = 0.f, a2 = 0.f, a3 = 0.f;
#pragma unroll
    for (int kh = 0; kh < 5; ++kh) {
        const float4* rowp = (const float4*)(sx + (r + kh)*36 + cg);
        float4 v0 = rowp[0], v1 = rowp[1];
        float xv[8] = {v0.x, v0.y, v0.z, v0.w, v1.x, v1.y, v1.z, v1.w};
#pragma unroll
        for (int kw = 0; kw < 5; ++kw) {
            float wv = sm[kh*5 + kw];
            a0 = fmaf(xv[kw+0], wv, a0);
            a1 = fmaf(xv[kw+1], wv, a1);
            a2 = fmaf(xv[kw+2], wv, a2);
            a3 = fmaf(xv[kw+3], wv, a3);
        }
    }
    size_t oidx = ((size_t)(b*EXC_ + e))*HW_ + (h0 + r)*WW + w0 + cg;
    *(float4*)(out + oidx) = make_float4(a0, a1, a2, a3);
}

// ---------------------------------------------------------------------------
// scatter_ee with LDS x-staging. Resolves the R7/R8 tension:
//   R7 (thread=position): coalesced reads but same-winner LDS collisions.
//   R8 (thread=channel):  conflict-free LDS but 64-line lane-strided reads.
// Here: stage x[b, 0:96, chunk of 32 pos] into LDS with COALESCED loads,
// then transposed accumulation (lane=channel) reads x from LDS (stride 33
// -> bank (c+off)%32, conflict-free) and does consecutive-address atomics
// into s_yx (stride 96, lanes=c -> 2/bank, free). win/val preloaded once.
// ---------------------------------------------------------------------------
__global__ __launch_bounds__(256) void scatter_ee_kernel(
    const float* __restrict__ x, const int* __restrict__ win_e,
    const float* __restrict__ val_e, float* __restrict__ parts)
{
    __shared__ float s_yx[EXC_*CIN_];   // 9792  [e][c] stride 96
    __shared__ float s_yu[EXC_];        // 102
    __shared__ float s_xs[CIN_*33];     // 3168  [c][pos] stride 33
    __shared__ float s_val[256];
    __shared__ int   s_win[256];
    const int t = threadIdx.x;
    for (int i = t; i < EXC_*CIN_; i += 256) s_yx[i] = 0.f;
    if (t < EXC_) s_yu[t] = 0.f;
    {
        int p = blockIdx.x*256 + t;
        s_win[t] = win_e[p];
        s_val[t] = val_e[p];
    }
    const int p0  = blockIdx.x * 256;
    const int b   = p0 >> 12;
    const int hw0 = p0 & 4095;
    const float* xb = x + (size_t)b*CIN_*HW_ + hw0;
    const int c = (t < 96) ? t : t - 96;   // accumulate role (t<192)
    const int h = (t < 96) ? 0 : 1;

    for (int ch = 0; ch < 8; ++ch) {
        __syncthreads();   // covers init on ch==0; stage-overwrite later
        // stage 96 x 32 floats, coalesced (rows of 8 float4)
#pragma unroll
        for (int it = 0; it < 3; ++it) {
            int idx = t + it*256;
            if (idx < 768) {
                int cr = idx >> 3, c4 = idx & 7;
                float4 v = *(const float4*)(xb + (size_t)cr*HW_ + ch*32 + c4*4);
                float* d = &s_xs[cr*33 + c4*4];
                d[0] = v.x; d[1] = v.y; d[2] = v.z; d[3] = v.w;
            }
        }
        __syncthreads();
        if (t < 192) {
#pragma unroll
            for (int k = 0; k < 16; ++k) {
                int pos = ch*32 + h*16 + k;
                float ve = s_val[pos]; int we = s_win[pos];
                atomicAdd(&s_yx[we*CIN_ + c], ve * s_xs[c*33 + h*16 + k]);
                if (c == 0) atomicAdd(&s_yu[we], ve);
            }
        }
    }
    __syncthreads();
    float* dee = parts + (size_t)blockIdx.x * NEE;
    for (int i = t; i < EXC_*CIN_; i += 256) dee[i] = s_yx[i];
    if (t < EXC_) dee[EXC_*CIN_ + t] = s_yu[t];
}

// ---------------------------------------------------------------------------
// scatter_iei: ei pairs (LDS atomics, tiny) + ie with y-staging (same
// staged-transpose pattern as scatter_ee). s_ie stride 27 (odd) -> lanes
// with distinct e hit distinct banks; no same-address collisions (lane=e).
// ---------------------------------------------------------------------------
__global__ __launch_bounds__(256) void scatter_iei_kernel(
    const float* __restrict__ y, const int* __restrict__ win_e,
    const float* __restrict__ val_e, const int* __restrict__ win_i,
    const float* __restrict__ val_i, float* __restrict__ yx_ei,
    float* __restrict__ yu_i, float* __restrict__ parts)
{
    __shared__ float s_ie[EXC_*27];           // 2754  [e][i] stride 27
    __shared__ float s_ei[INH_*EXC_ + INH_];  // 2678
    __shared__ float s_ys[EXC_*33];           // 3366  [e][pos] stride 33
    __shared__ float s_val[256];
    __shared__ int   s_win[256];
    const int t = threadIdx.x;
    for (int i = t; i < EXC_*27; i += 256) s_ie[i] = 0.f;
    for (int i = t; i < INH_*EXC_ + INH_; i += 256) s_ei[i] = 0.f;
    {
        int p = blockIdx.x*256 + t;
        s_win[t] = win_i[p];
        s_val[t] = val_i[p];
    }
    __syncthreads();

    // phase A: ei pairs
    {
        int p = blockIdx.x*256 + t;
        int we = win_e[p]; float ve = val_e[p];
        int wi = s_win[t]; float vi = s_val[t];
        atomicAdd(&s_ei[wi*EXC_ + we], ve*vi);
        atomicAdd(&s_ei[INH_*EXC_ + wi], fabsf(vi));
    }

    const int p0  = blockIdx.x * 256;
    const int b   = p0 >> 12;
    const int hw0 = p0 & 4095;
    const float* yb = y + (size_t)b*EXC_*HW_ + hw0;
    const int e = (t < 102) ? t : t - 102;   // accumulate role (t<204)
    const int h = (t < 102) ? 0 : 1;

    for (int ch = 0; ch < 8; ++ch) {
        __syncthreads();
        // stage 102 x 32 floats (816 float4)
#pragma unroll
        for (int it = 0; it < 4; ++it) {
            int idx = t + it*256;
            if (idx < 816) {
                int er = idx >> 3, c4 = idx & 7;
                float4 v = *(const float4*)(yb + (size_t)er*HW_ + ch*32 + c4*4);
                float* d = &s_ys[er*33 + c4*4];
                d[0] = v.x; d[1] = v.y; d[2] = v.z; d[3] = v.w;
            }
        }
        __syncthreads();
        if (t < 204) {
#pragma unroll
            for (int k = 0; k < 16; ++k) {
                int pos = ch*32 + h*16 + k;
                float vi = s_val[pos];
                if (vi != 0.f) {
                    int wi = s_win[pos];
                    atomicAdd(&s_ie[e*27 + wi], vi * s_ys[e*33 + h*16 + k]);
                }
            }
        }
    }
    __syncthreads();

    for (int i = t; i < INH_*EXC_ + INH_; i += 256) {
        float v = s_ei[i];
        if (v != 0.f) {
            if (i < INH_*EXC_) atomicAdd(&yx_ei[i], v);
            else               atomicAdd(&yu_i[i - INH_*EXC_], v);
        }
    }
    float* die = parts + (size_t)blockIdx.x * NIE;
    for (int i = t; i < EXC_*INH_; i += 256) {
        int ee = i / INH_, ii = i - ee*INH_;
        die[i] = s_ie[ee*27 + ii];
    }
}

// One reduce for both partial sets (NPART=512 each).
__global__ __launch_bounds__(256) void reduce_all_kernel(
    const float* __restrict__ parts_ee, const float* __restrict__ parts_ie,
    float* __restrict__ yx_ee, float* __restrict__ yx_ie)
{
    __shared__ float s[256];
    int col = blockIdx.x*64 + (threadIdx.x & 63);
    int g = threadIdx.x >> 6;
    const float* P; float* D; int n, i;
    if (col < NEE) { P = parts_ee; D = yx_ee; n = NEE; i = col; }
    else           { P = parts_ie; D = yx_ie; n = NIE; i = col - NEE; }
    float a = 0.f;
    if (col < NEE + NIE) {
        for (int j = g*(NPART/4); j < (g+1)*(NPART/4); ++j)
            a += P[(size_t)j*n + i];
    }
    s[threadIdx.x] = a;
    __syncthreads();
    if (threadIdx.x < 64 && col < NEE + NIE)
        D[i] = s[threadIdx.x] + s[threadIdx.x+64] + s[threadIdx.x+128] + s[threadIdx.x+192];
}

// fused absmax over the three update matrices (nonneg bits int-monotonic)
__global__ __launch_bounds__(256) void upd_absmax3(
    const float* __restrict__ yx_ee, const float* __restrict__ yu_e,
    const float* __restrict__ w_ee,
    const float* __restrict__ yx_ei, const float* __restrict__ yu_i,
    const float* __restrict__ w_ei,
    const float* __restrict__ yx_ie, const float* __restrict__ w_ie,
    unsigned int* __restrict__ amax)
{
    float m0 = 0.f, m1 = 0.f, m2 = 0.f;
    for (int idx = blockIdx.x*256 + threadIdx.x; idx < N1U + N2U + N3U;
         idx += gridDim.x*256) {
        if (idx < N1U) {
            int ec = idx / 25; int e = ec / CIN_;
            m0 = fmaxf(m0, fabsf(yx_ee[ec] - yu_e[e]*w_ee[idx]));
        } else if (idx < N1U + N2U) {
            int j = idx - N1U; int ec = j / 25; int e = ec / EXC_;
            m1 = fmaxf(m1, fabsf(yx_ei[ec] - yu_i[e]*w_ei[j]));
        } else {
            int j = idx - N1U - N2U; int ec = j / 25; int e = ec / INH_;
            m2 = fmaxf(m2, fabsf(yx_ie[ec] - yu_e[e]*w_ie[j]));
        }
    }
    __shared__ unsigned int s0, s1, s2;
    if (threadIdx.x == 0) { s0 = 0u; s1 = 0u; s2 = 0u; }
    __syncthreads();
    atomicMax(&s0, __float_as_uint(m0));
    atomicMax(&s1, __float_as_uint(m1));
    atomicMax(&s2, __float_as_uint(m2));
    __syncthreads();
    if (threadIdx.x == 0) {
        atomicMax(&amax[0], s0);
        atomicMax(&amax[1], s1);
        atomicMax(&amax[2], s2);
    }
}

__global__ __launch_bounds__(256) void upd_write3(
    const float* __restrict__ yx_ee, const float* __restrict__ yu_e,
    const float* __restrict__ w_ee,
    const float* __restrict__ yx_ei, const float* __restrict__ yu_i,
    const float* __restrict__ w_ei,
    const float* __restrict__ yx_ie, const float* __restrict__ w_ie,
    const unsigned int* __restrict__ amax,
    float* __restrict__ out_ee, float* __restrict__ out_ei,
    float* __restrict__ out_ie)
{
    int idx = blockIdx.x*256 + threadIdx.x;
    if (idx >= N1U + N2U + N3U) return;
    if (idx < N1U) {
        int ec = idx / 25; int e = ec / CIN_;
        float v = yx_ee[ec] - yu_e[e]*w_ee[idx];
        out_ee[idx] = v / (__uint_as_float(amax[0]) + 1e-8f);
    } else if (idx < N1U + N2U) {
        int j = idx - N1U; int ec = j / 25; int e = ec / EXC_;
        float v = yx_ei[ec] - yu_i[e]*w_ei[j];
        out_ei[j] = v / (__uint_as_float(amax[1]) + 1e-8f);
    } else {
        int j = idx - N1U - N2U; int ec = j / 25; int e = ec / INH_;
        float v = yx_ie[ec] - yu_e[e]*w_ie[j];
        out_ie[j] = v / (__uint_as_float(amax[2]) + 1e-8f);
    }
}

extern "C" void kernel_launch(void* const* d_in, const int* in_sizes, int n_in,
                              void* d_out, int out_size, void* d_ws, size_t ws_size,
                              hipStream_t stream)
{
    const float* x    = (const float*)d_in[0];
    const float* w_ee = (const float*)d_in[1];
    const float* w_ei = (const float*)d_in[2];
    const float* w_ie = (const float*)d_in[3];
    const float* smk  = (const float*)d_in[4];
    float* out = (float*)d_out;

    const size_t SZ_YE   = (size_t)B_*EXC_*HW_;     // floats  (53.5 MB)
    const size_t SZ_YEBF = (size_t)B_*HW_*128;      // shorts  (33.6 MB)
    const size_t SZ_XBF  = (size_t)B_*HW_*96;       // shorts  (25.2 MB)
    const size_t SZ_W    = 460800;                  // shorts
    const size_t need_direct =
        SZ_YE*4 + SZ_YEBF*2 + SZ_XBF*2 + SZ_W*2 + (size_t)NPOS*16 + 16000*4;
    const bool direct = (ws_size >= need_direct);

    float* y_e  = (float*)d_ws;
    short* yebf; short* R;
    if (direct) {
        yebf = (short*)(y_e + SZ_YE);
        R    = yebf + SZ_YEBF;                       // xbf, later yibf
    } else {
        yebf = nullptr;
        R    = (short*)(y_e + SZ_YE);                // yibf(8.4MB) then big R
    }
    short* yibf = direct ? R : R;
    short* bigR = direct ? R : (R + (size_t)B_*HW_*32);
    short* wee  = direct ? (R + SZ_XBF) : (bigR + (size_t)16777216);
    short* wei  = wee + 268800;
    short* wie  = wei + 102400;
    int*   win_e = (int*)(wie + 89600);
    float* val_e = (float*)(win_e + NPOS);
    int*   win_i = (int*)(val_e + NPOS);
    float* val_i = (float*)(win_i + NPOS);
    float* yx_ee = val_i + NPOS;                     // 9792
    float* yu_e  = yx_ee + EXC_*CIN_;                // 102
    float* yx_ie = yu_e + EXC_;                      // 2652
    float* yx_ei = yx_ie + EXC_*INH_;                // 2652
    float* yu_i  = yx_ei + INH_*EXC_;                // 26
    unsigned int* amax = (unsigned int*)(yu_i + INH_);   // 3
    // scatter partials overlay y_e (y_pre dead after smconv):
    // 512*(9894+2652)*4 = 25.7MB <= 53.5MB
    float* parts_ee = y_e;                           // NPART*NEE
    float* parts_ie = parts_ee + (size_t)NPART*NEE;  // NPART*NIE

    // ---- 1: pack weights + x + zero atomic targets ----
    pack_all<<<3849, 256, 0, stream>>>(w_ee, w_ei, w_ie, x, wee, bigR, yx_ei);

    if (direct) {
        conv_mfma<96, 112, 7, EXC_, 3, false, false, true, 128, true>
            <<<dim3(16, 1, B_), 256, 0, stream>>>(bigR, wee, nullptr, y_e, yebf,
                                                  win_e, val_e);
        conv_mfma<128, 32, 2, INH_, 4, true, false, false, 32, true>
            <<<dim3(16, 1, B_), 256, 0, stream>>>(yebf, wei, nullptr, nullptr,
                                                  yibf, win_i, val_i);
        conv_mfma<32, 112, 7, EXC_, 1, false, true, true, 0, false>
            <<<dim3(16, 1, B_), 256, 0, stream>>>(yibf, wie, y_e, y_e, nullptr,
                                                  nullptr, nullptr);
    } else {
        conv_mfma<96, 112, 7, EXC_, 3, false, false, true, 0, true>
            <<<dim3(16, 1, B_), 256, 0, stream>>>(bigR, wee, nullptr, y_e, nullptr,
                                                  win_e, val_e);
        pack_nhwc<EXC_, 128><<<dim3(64, 1, B_), 256, 0, stream>>>(y_e, bigR);
        conv_mfma<128, 32, 2, INH_, 4, true, false, false, 32, true>
            <<<dim3(16, 1, B_), 256, 0, stream>>>(bigR, wei, nullptr, nullptr,
                                                  yibf, win_i, val_i);
        conv_mfma<32, 112, 7, EXC_, 1, false, true, true, 0, false>
            <<<dim3(16, 1, B_), 256, 0, stream>>>(yibf, wie, y_e, y_e, nullptr,
                                                  nullptr, nullptr);
    }

    // ---- 5: y = depthwise sm conv (zero pad) -> d_out chunk 0 ----
    smconv_v2<<<dim3(4, EXC_, B_), 256, 0, stream>>>(y_e, smk, out);

    // ---- 6-7: staged-transpose Hebbian scatters ----
    scatter_ee_kernel<<<NPART, 256, 0, stream>>>(x, win_e, val_e, parts_ee);
    scatter_iei_kernel<<<NPART, 256, 0, stream>>>(out, win_e, val_e, win_i,
                                                  val_i, yx_ei, yu_i, parts_ie);

    // ---- 8: reduce partials ----
    reduce_all_kernel<<<(NEE + NIE + 63)/64, 256, 0, stream>>>(
        parts_ee, parts_ie, yx_ee, yx_ie);

    // ---- 9-10: upd normalization ----
    upd_absmax3<<<480, 256, 0, stream>>>(yx_ee, yu_e, w_ee, yx_ei, yu_i, w_ei,
                                         yx_ie, w_ie, amax);
    float* out_ee = out + (size_t)B_*EXC_*HW_;
    float* out_ei = out_ee + N1U;
    float* out_ie = out_ei + N2U;
    upd_write3<<<(N1U + N2U + N3U + 255)/256, 256, 0, stream>>>(
        yx_ee, yu_e, w_ee, yx_ei, yu_i, w_ei, yx_ie, w_ie, amax,
        out_ee, out_ei, out_ie);
}

// Round 10
// 534.046 us; speedup vs baseline: 1.0506x; 1.0506x over previous
//
#include <hip/hip_runtime.h>

#define B_    32
#define CIN_  96
#define EXC_  102
#define INH_  26
#define HH    64
#define WW    64
#define HW_   4096
#define NPOS  (B_*HW_)   // 131072
#define NPART 512        // partial buffers per scatter
#define NEE   (EXC_*CIN_ + EXC_)      // 9894: yx_ee + yu_e
#define NIE   (EXC_*INH_)             // 2652
#define NEI   (INH_*EXC_)             // 2652
#define N1U   (EXC_*CIN_*25)          // 244800
#define N2U   (INH_*EXC_*25)          // 66300
#define N3U   (EXC_*INH_*25)          // 66300

typedef short bf8 __attribute__((ext_vector_type(8)));
typedef float f32x4 __attribute__((ext_vector_type(4)));

__device__ __forceinline__ int refl(int i) {
    if (i < 0) i = -i;
    if (i > 63) i = 126 - i;
    return i;
}

__device__ __forceinline__ short f2bf(float f) {
    unsigned u = __float_as_uint(f);
    return (short)((u + 0x7fffu + ((u >> 16) & 1u)) >> 16);
}

// ---------------------------------------------------------------------------
// Fused front-end: pack all 3 weight tensors + pack x to NHWC bf16 + zero the
// small atomic-target region.
// ---------------------------------------------------------------------------
__global__ __launch_bounds__(256) void pack_all(
    const float* __restrict__ w_ee, const float* __restrict__ w_ei,
    const float* __restrict__ w_ie, const float* __restrict__ x,
    short* __restrict__ wdst, short* __restrict__ xdst,
    float* __restrict__ zreg)
{
    const int blk = blockIdx.x;
    if (blk < 1800) {
        int gi = blk*256 + threadIdx.x;
        if (gi >= 460800) return;
        const float* src; int N, C, NPAD, CPAD; int idx;
        if (gi < 268800)      { src = w_ee; N = 102; C = 96;  NPAD = 112; CPAD = 96;  idx = gi; }
        else if (gi < 371200) { src = w_ei; N = 26;  C = 102; NPAD = 32;  CPAD = 128; idx = gi - 268800; }
        else                  { src = w_ie; N = 102; C = 26;  NPAD = 112; CPAD = 32;  idx = gi - 371200; }
        int tap = idx / (NPAD*CPAD);
        int rem = idx - tap*(NPAD*CPAD);
        int n = rem / CPAD, c = rem - n*CPAD;
        float f = (n < N && c < C) ? src[((size_t)n*C + c)*25 + tap] : 0.f;
        wdst[gi] = f2bf(f);
    } else if (blk < 3848) {
        int bb = blk - 1800;
        int b = bb >> 6, bx = bb & 63;
        const int pos = bx*64 + (threadIdx.x & 63);
        const int cg0 = threadIdx.x >> 6;
        for (int cg = cg0; cg < 96/8; cg += 4) {
            bf8 v;
#pragma unroll
            for (int j = 0; j < 8; ++j)
                v[j] = f2bf(x[((size_t)b*CIN_ + cg*8 + j)*HW_ + pos]);
            *(bf8*)(&xdst[((size_t)b*HW_ + pos)*96 + cg*8]) = v;
        }
    } else {
        for (int i = threadIdx.x; i < INH_*EXC_ + INH_ + 3; i += 256) zreg[i] = 0.f;
    }
}

// NCHW fp32 -> NHWC bf16 pack (fallback path only)
template<int C, int CPAD>
__global__ __launch_bounds__(256) void pack_nhwc(
    const float* __restrict__ src, short* __restrict__ dst)
{
    const int b = blockIdx.z;
    const int pos = blockIdx.x*64 + (threadIdx.x & 63);
    const int cg0 = threadIdx.x >> 6;
    for (int cg = cg0; cg < CPAD/8; cg += 4) {
        bf8 v;
#pragma unroll
        for (int j = 0; j < 8; ++j) {
            int c = cg*8 + j;
            float f = (c < C) ? src[((size_t)b*C + c)*HW_ + pos] : 0.f;
            v[j] = f2bf(f);
        }
        *(bf8*)(&dst[((size_t)b*HW_ + pos)*CPAD + cg*8]) = v;
    }
}

// ---------------------------------------------------------------------------
// MFMA implicit-GEMM 5x5 conv, reflect pad. Block = 16x16 spatial tile,
// 256 thr = 4 waves; wave = 4 Mtiles(rows) x NT Ntiles(16 ch each).
// (R4 lesson: 4 Mtiles/wave required to amortize B-fragment loads.)
// ---------------------------------------------------------------------------
template<int CPAD, int NPAD, int NT, int COUT, int NCHUNK,
         bool RELU, bool ADDIN, bool WFLOAT, int OCPAD, bool WTA>
__global__ __launch_bounds__(256, 2) void conv_mfma(
    const short* __restrict__ src, const short* __restrict__ wgt,
    const float* __restrict__ addin, float* __restrict__ out,
    short* __restrict__ nhwc_out, int* __restrict__ win,
    float* __restrict__ val)
{
    __shared__ __align__(16) short sA[400*40];
    const int t  = threadIdx.x;
    const int bx = blockIdx.x;
    const int b  = blockIdx.z;
    const int h0 = (bx >> 2) * 16;
    const int w0 = (bx &  3) * 16;
    const int lane = t & 63;
    const int wv = t >> 6;
    const int nh = lane & 15;
    const int q  = lane >> 4;

    int goff[7], loff[7];
#pragma unroll
    for (int s = 0; s < 7; ++s) {
        int i = t + 256*s;
        if (i < 1600) {
            int rec = i >> 2, seg = i & 3;
            int lh = rec / 20, lw = rec - lh*20;
            int gh = refl(h0 - 2 + lh), gw = refl(w0 - 2 + lw);
            goff[s] = (b*HW_ + gh*WW + gw) * CPAD + seg*8;
            loff[s] = rec*40 + seg*8;
        } else { goff[s] = 0; loff[s] = -1; }
    }

    f32x4 acc[4][NT];
#pragma unroll
    for (int mt = 0; mt < 4; ++mt)
#pragma unroll
        for (int nt = 0; nt < NT; ++nt) {
            f32x4 z = {0.f, 0.f, 0.f, 0.f};
            acc[mt][nt] = z;
        }

    int abase[4];
#pragma unroll
    for (int mt = 0; mt < 4; ++mt)
        abase[mt] = ((wv*4 + mt)*20 + nh)*40 + q*8;

    for (int ck = 0; ck < NCHUNK; ++ck) {
        const int c0 = ck*32;
        __syncthreads();
#pragma unroll
        for (int s = 0; s < 7; ++s)
            if (loff[s] >= 0)
                *(bf8*)(&sA[loff[s]]) = *(const bf8*)(&src[goff[s] + c0]);
        __syncthreads();
        const short* wch = wgt + c0 + nh*CPAD + q*8;
        for (int dh = 0; dh < 5; ++dh) {
#pragma unroll
            for (int dw = 0; dw < 5; ++dw) {
                const int tap = dh*5 + dw;
                bf8 bfr[NT];
#pragma unroll
                for (int nt = 0; nt < NT; ++nt)
                    bfr[nt] = *(const bf8*)(&wch[(size_t)(tap*NPAD + nt*16)*CPAD]);
                bf8 afr[4];
#pragma unroll
                for (int mt = 0; mt < 4; ++mt)
                    afr[mt] = *(const bf8*)(&sA[abase[mt] + (dh*20 + dw)*40]);
#pragma unroll
                for (int mt = 0; mt < 4; ++mt)
#pragma unroll
                    for (int nt = 0; nt < NT; ++nt)
                        acc[mt][nt] = __builtin_amdgcn_mfma_f32_16x16x32_bf16(
                            afr[mt], bfr[nt], acc[mt][nt], 0, 0, 0);
            }
        }
    }

    // epilogue: D row (q*4+reg) = position col, D col (nh) = channel
#pragma unroll
    for (int mt = 0; mt < 4; ++mt) {
        const int rowi = h0 + wv*4 + mt;
#pragma unroll
        for (int nt = 0; nt < NT; ++nt) {
            const int chn = nt*16 + nh;
            if (WFLOAT && chn < COUT) {
                size_t obase = ((size_t)(b*COUT + chn))*HW_ + rowi*WW + w0 + q*4;
#pragma unroll
                for (int r = 0; r < 4; ++r) {
                    float v = acc[mt][nt][r];
                    if (RELU) v = fmaxf(v, 0.f);
                    if (ADDIN) v += addin[obase + r];
                    out[obase + r] = v;
                }
            }
            if (OCPAD > 0) {
#pragma unroll
                for (int r = 0; r < 4; ++r) {
                    float v = acc[mt][nt][r];
                    if (RELU) v = fmaxf(v, 0.f);
                    int pos = rowi*WW + w0 + q*4 + r;
                    nhwc_out[((size_t)b*HW_ + pos)*OCPAD + chn] = f2bf(v);
                }
            }
        }
        if (OCPAD > NT*16) {
#pragma unroll
            for (int r = 0; r < 4; ++r) {
                int pos = rowi*WW + w0 + q*4 + r;
                for (int ct = NT*16 + nh; ct < OCPAD; ct += 16)
                    nhwc_out[((size_t)b*HW_ + pos)*OCPAD + ct] = 0;
            }
        }
        if (WTA) {
#pragma unroll
            for (int r = 0; r < 4; ++r) {
                float bv = -3.402823e38f; int bc = 0;
#pragma unroll
                for (int nt = 0; nt < NT; ++nt) {
                    const int chn = nt*16 + nh;
                    float v = acc[mt][nt][r];
                    if (RELU) v = fmaxf(v, 0.f);
                    if (chn < COUT && v > bv) { bv = v; bc = chn; }
                }
#pragma unroll
                for (int off = 1; off < 16; off <<= 1) {
                    float ov = __shfl_xor(bv, off);
                    int   oc = __shfl_xor(bc, off);
                    if (ov > bv || (ov == bv && oc < bc)) { bv = ov; bc = oc; }
                }
                if (nh == 0) {
                    int p = b*HW_ + rowi*WW + w0 + q*4 + r;
                    win[p] = bc; val[p] = bv;
                }
            }
        }
    }
}

// Depthwise 5x5 surround-modulation conv, ZERO padding. 32x32 tile, TW=4.
__global__ __launch_bounds__(256) void smconv_v2(
    const float* __restrict__ in, const float* __restrict__ sm,
    float* __restrict__ out)
{
    __shared__ __align__(16) float sx[36*36];
    const int tid = threadIdx.x;
    const int tile = blockIdx.x;
    const int e = blockIdx.y;
    const int b = blockIdx.z;
    const int h0 = (tile >> 1) * 32, w0 = (tile & 1) * 32;
    const int r  = tid >> 3;
    const int cg = (tid & 7) * 4;
    const float* inc = in + ((size_t)(b*EXC_ + e))*HW_;
#pragma unroll
    for (int it = 0; it < 6; ++it) {
        int i = tid + it*256;
        if (i < 1296) {
            int lh = i / 36, lw = i - lh*36;
            int gh = h0 - 2 + lh, gw = w0 - 2 + lw;
            float v = 0.f;
            if (gh >= 0 && gh < HH && gw >= 0 && gw < WW) v = inc[gh*WW + gw];
            sx[i] = v;
        }
    }
    __syncthreads();
    float a0 = 0.f, a1 = 0.f, a2 = 0.f, a3 = 0.f;
#pragma unroll
    for (int kh = 0; kh < 5; ++kh) {
        const float4* rowp = (const float4*)(sx + (r + kh)*36 + cg);
        float4 v0 = rowp[0], v1 = rowp[1];
        float xv[8] = {v0.x, v0.y, v0.z, v0.w, v1.x, v1.y, v1.z, v1.w};
#pragma unroll
        for (int kw = 0; kw < 5; ++kw) {
            float wv = sm[kh*5 + kw];
            a0 = fmaf(xv[kw+0], wv, a0);
            a1 = fmaf(xv[kw+1], wv, a1);
            a2 = fmaf(xv[kw+2], wv, a2);
            a3 = fmaf(xv[kw+3], wv, a3);
        }
    }
    size_t oidx = ((size_t)(b*EXC_ + e))*HW_ + (h0 + r)*WW + w0 + cg;
    *(float4*)(out + oidx) = make_float4(a0, a1, a2, a3);
}

// ---------------------------------------------------------------------------
// scatter_ee, staged + position-permuted:
//  - stage 16 x-channels x 256 pos into LDS with COALESCED loads
//  - thread owns position perm(t)=t*75 mod 256: consecutive lanes sit 75
//    pixels apart -> winners decorrelated -> same-address atomic multiplicity
//    drops from ~16 (clustered, R7) to ~2 (birthday).
//  - s_yx stride 97: bank = (winner + c) % 32, distinct winners -> distinct
//    banks. stage stride 258: read bank = (2c + pp) % 32, 2-way (free).
// f32 end-to-end (precision identical to all passing rounds).
// ---------------------------------------------------------------------------
__global__ __launch_bounds__(256) void scatter_ee_kernel(
    const float* __restrict__ x, const int* __restrict__ win_e,
    const float* __restrict__ val_e, float* __restrict__ parts)
{
    __shared__ float s_yx[EXC_*97];     // 39.6 KB
    __shared__ float s_yu[EXC_];
    __shared__ float s_xs[16*258];      // 16.5 KB
    __shared__ float s_val[256];
    __shared__ int   s_win[256];
    const int t = threadIdx.x;
    for (int i = t; i < EXC_*97; i += 256) s_yx[i] = 0.f;
    if (t < EXC_) s_yu[t] = 0.f;
    {
        int p = blockIdx.x*256 + t;
        s_win[t] = win_e[p];
        s_val[t] = val_e[p];
    }
    __syncthreads();
    const int pp = (t*75) & 255;        // bijection (75 odd)
    const int myw = s_win[pp];
    const float myv = s_val[pp];
    atomicAdd(&s_yu[myw], myv);

    const int p0  = blockIdx.x * 256;
    const int b   = p0 >> 12;
    const int hw0 = p0 & 4095;
    const float* xb = x + (size_t)b*CIN_*HW_ + hw0;

    for (int ch = 0; ch < 6; ++ch) {
        __syncthreads();
        // stage: it-th round loads channel ch*16+it, pos t (coalesced 256B)
#pragma unroll
        for (int it = 0; it < 16; ++it)
            s_xs[it*258 + t] = xb[(size_t)(ch*16 + it)*HW_ + t];
        __syncthreads();
#pragma unroll
        for (int c = 0; c < 16; ++c)
            atomicAdd(&s_yx[myw*97 + ch*16 + c], myv * s_xs[c*258 + pp]);
    }
    __syncthreads();
    float* dee = parts + (size_t)blockIdx.x * NEE;
    for (int i = t; i < EXC_*CIN_; i += 256) {
        int e = i / CIN_, c = i - e*CIN_;
        dee[i] = s_yx[e*97 + c];
    }
    if (t < EXC_) dee[EXC_*CIN_ + t] = s_yu[t];
}

// ---------------------------------------------------------------------------
// scatter_iei, same staged+permuted structure for the ie sum; ei pairs are
// one atomic per position (perm'd). s_ie stride 27: distinct winners ->
// distinct banks; same-winner same-address ~2.5-way (26 bins / 64 lanes).
// ---------------------------------------------------------------------------
__global__ __launch_bounds__(256) void scatter_iei_kernel(
    const float* __restrict__ y, const int* __restrict__ win_e,
    const float* __restrict__ val_e, const int* __restrict__ win_i,
    const float* __restrict__ val_i, float* __restrict__ yx_ei,
    float* __restrict__ yu_i, float* __restrict__ parts)
{
    __shared__ float s_ie[EXC_*27];           // 11.0 KB
    __shared__ float s_ei[INH_*EXC_ + INH_];  // 10.7 KB
    __shared__ float s_ys[17*258];            // 17.5 KB
    __shared__ float s_val[256];
    __shared__ int   s_win[256];
    const int t = threadIdx.x;
    for (int i = t; i < EXC_*27; i += 256) s_ie[i] = 0.f;
    for (int i = t; i < INH_*EXC_ + INH_; i += 256) s_ei[i] = 0.f;
    {
        int p = blockIdx.x*256 + t;
        s_win[t] = win_i[p];
        s_val[t] = val_i[p];
    }
    __syncthreads();
    const int pp = (t*75) & 255;
    const int myw = s_win[pp];
    const float myv = s_val[pp];
    {
        int p = blockIdx.x*256 + pp;
        int we = win_e[p]; float ve = val_e[p];
        atomicAdd(&s_ei[myw*EXC_ + we], ve*myv);
        atomicAdd(&s_ei[INH_*EXC_ + myw], fabsf(myv));
    }

    const int p0  = blockIdx.x * 256;
    const int b   = p0 >> 12;
    const int hw0 = p0 & 4095;
    const float* yb = y + (size_t)b*EXC_*HW_ + hw0;

    for (int ch = 0; ch < 6; ++ch) {
        __syncthreads();
#pragma unroll
        for (int it = 0; it < 17; ++it)
            s_ys[it*258 + t] = yb[(size_t)(ch*17 + it)*HW_ + t];
        __syncthreads();
        if (myv != 0.f) {
#pragma unroll
            for (int c = 0; c < 17; ++c)
                atomicAdd(&s_ie[(ch*17 + c)*27 + myw], myv * s_ys[c*258 + pp]);
        }
    }
    __syncthreads();
    for (int i = t; i < INH_*EXC_ + INH_; i += 256) {
        float v = s_ei[i];
        if (v != 0.f) {
            if (i < INH_*EXC_) atomicAdd(&yx_ei[i], v);
            else               atomicAdd(&yu_i[i - INH_*EXC_], v);
        }
    }
    float* die = parts + (size_t)blockIdx.x * NIE;
    for (int i = t; i < EXC_*INH_; i += 256) {
        int e = i / INH_, ii = i - e*INH_;
        die[i] = s_ie[e*27 + ii];
    }
}

// ---------------------------------------------------------------------------
// Fused reduce + absmax. Column ranges:
//   [0, NEE)            : reduce parts_ee col -> yx_ee / yu_e; ee absmax
//                         (needs yu_e[e]: redundantly re-reduced per thread)
//   [NEE, NEE+NIE)      : reduce parts_ie col -> yx_ie; ie absmax (+ yu_e)
//   [NEE+NIE, +NEI)     : no reduction; ei absmax from global yx_ei/yu_i
// ---------------------------------------------------------------------------
__global__ __launch_bounds__(256) void reduce_absmax_kernel(
    const float* __restrict__ parts_ee, const float* __restrict__ parts_ie,
    const float* __restrict__ yx_ei, const float* __restrict__ yu_i,
    const float* __restrict__ w_ee, const float* __restrict__ w_ei,
    const float* __restrict__ w_ie,
    float* __restrict__ yx_ee, float* __restrict__ yx_ie,
    unsigned int* __restrict__ amax)
{
    __shared__ float s[256], su[256];
    __shared__ unsigned int sm0, sm1, sm2;
    const int t = threadIdx.x;
    if (t == 0) { sm0 = 0u; sm1 = 0u; sm2 = 0u; }
    int col = blockIdx.x*64 + (t & 63);
    int g = t >> 6;
    float a = 0.f, ayu = 0.f;
    if (col < NEE) {
        int e = (col < EXC_*CIN_) ? col / CIN_ : -1;
        for (int j = g*(NPART/4); j < (g+1)*(NPART/4); ++j) {
            a += parts_ee[(size_t)j*NEE + col];
            if (e >= 0) ayu += parts_ee[(size_t)j*NEE + EXC_*CIN_ + e];
        }
    } else if (col < NEE + NIE) {
        int j2 = col - NEE;
        int e = j2 / INH_;
        for (int j = g*(NPART/4); j < (g+1)*(NPART/4); ++j) {
            a   += parts_ie[(size_t)j*NIE + j2];
            ayu += parts_ee[(size_t)j*NEE + EXC_*CIN_ + e];
        }
    }
    s[t] = a; su[t] = ayu;
    __syncthreads();
    if (t < 64) {
        float m0 = 0.f, m1 = 0.f, m2 = 0.f;
        if (col < NEE + NIE + NEI) {
            if (col < NEE) {
                float yx = s[t] + s[t+64] + s[t+128] + s[t+192];
                yx_ee[col] = yx;   // includes yu_e tail columns
                if (col < EXC_*CIN_) {
                    float yu = su[t] + su[t+64] + su[t+128] + su[t+192];
                    const float* wp = w_ee + (size_t)col*25;
#pragma unroll
                    for (int tap = 0; tap < 25; ++tap)
                        m0 = fmaxf(m0, fabsf(yx - yu*wp[tap]));
                }
            } else if (col < NEE + NIE) {
                int j2 = col - NEE;
                float yx = s[t] + s[t+64] + s[t+128] + s[t+192];
                float yu = su[t] + su[t+64] + su[t+128] + su[t+192];
                yx_ie[j2] = yx;
                const float* wp = w_ie + (size_t)j2*25;
#pragma unroll
                for (int tap = 0; tap < 25; ++tap)
                    m2 = fmaxf(m2, fabsf(yx - yu*wp[tap]));
            } else {
                int k = col - NEE - NIE;
                float yx = yx_ei[k];
                float yu = yu_i[k / EXC_];
                const float* wp = w_ei + (size_t)k*25;
#pragma unroll
                for (int tap = 0; tap < 25; ++tap)
                    m1 = fmaxf(m1, fabsf(yx - yu*wp[tap]));
            }
        }
        atomicMax(&sm0, __float_as_uint(m0));
        atomicMax(&sm1, __float_as_uint(m1));
        atomicMax(&sm2, __float_as_uint(m2));
    }
    __syncthreads();
    if (t == 0) {
        if (sm0) atomicMax(&amax[0], sm0);
        if (sm1) atomicMax(&amax[1], sm1);
        if (sm2) atomicMax(&amax[2], sm2);
    }
}

__global__ __launch_bounds__(256) void upd_write3(
    const float* __restrict__ yx_ee, const float* __restrict__ yu_e,
    const float* __restrict__ w_ee,
    const float* __restrict__ yx_ei, const float* __restrict__ yu_i,
    const float* __restrict__ w_ei,
    const float* __restrict__ yx_ie, const float* __restrict__ w_ie,
    const unsigned int* __restrict__ amax,
    float* __restrict__ out_ee, float* __restrict__ out_ei,
    float* __restrict__ out_ie)
{
    int idx = blockIdx.x*256 + threadIdx.x;
    if (idx >= N1U + N2U + N3U) return;
    if (idx < N1U) {
        int ec = idx / 25; int e = ec / CIN_;
        float v = yx_ee[ec] - yu_e[e]*w_ee[idx];
        out_ee[idx] = v / (__uint_as_float(amax[0]) + 1e-8f);
    } else if (idx < N1U + N2U) {
        int j = idx - N1U; int ec = j / 25; int e = ec / EXC_;
        float v = yx_ei[ec] - yu_i[e]*w_ei[j];
        out_ei[j] = v / (__uint_as_float(amax[1]) + 1e-8f);
    } else {
        int j = idx - N1U - N2U; int ec = j / 25; int e = ec / INH_;
        float v = yx_ie[ec] - yu_e[e]*w_ie[j];
        out_ie[j] = v / (__uint_as_float(amax[2]) + 1e-8f);
    }
}

extern "C" void kernel_launch(void* const* d_in, const int* in_sizes, int n_in,
                              void* d_out, int out_size, void* d_ws, size_t ws_size,
                              hipStream_t stream)
{
    const float* x    = (const float*)d_in[0];
    const float* w_ee = (const float*)d_in[1];
    const float* w_ei = (const float*)d_in[2];
    const float* w_ie = (const float*)d_in[3];
    const float* smk  = (const float*)d_in[4];
    float* out = (float*)d_out;

    const size_t SZ_YE   = (size_t)B_*EXC_*HW_;     // floats  (53.5 MB)
    const size_t SZ_YEBF = (size_t)B_*HW_*128;      // shorts  (33.6 MB)
    const size_t SZ_XBF  = (size_t)B_*HW_*96;       // shorts  (25.2 MB)
    const size_t SZ_W    = 460800;                  // shorts
    const size_t need_direct =
        SZ_YE*4 + SZ_YEBF*2 + SZ_XBF*2 + SZ_W*2 + (size_t)NPOS*16 + 16000*4;
    const bool direct = (ws_size >= need_direct);

    float* y_e  = (float*)d_ws;
    short* yebf; short* R;
    if (direct) {
        yebf = (short*)(y_e + SZ_YE);
        R    = yebf + SZ_YEBF;                       // xbf, later yibf
    } else {
        yebf = nullptr;
        R    = (short*)(y_e + SZ_YE);                // yibf(8.4MB) then big R
    }
    short* yibf = direct ? R : R;
    short* bigR = direct ? R : (R + (size_t)B_*HW_*32);
    short* wee  = direct ? (R + SZ_XBF) : (bigR + (size_t)16777216);
    short* wei  = wee + 268800;
    short* wie  = wei + 102400;
    int*   win_e = (int*)(wie + 89600);
    float* val_e = (float*)(win_e + NPOS);
    int*   win_i = (int*)(val_e + NPOS);
    float* val_i = (float*)(win_i + NPOS);
    float* yx_ee = val_i + NPOS;                     // 9792
    float* yu_e  = yx_ee + EXC_*CIN_;                // 102
    float* yx_ie = yu_e + EXC_;                      // 2652
    float* yx_ei = yx_ie + EXC_*INH_;                // 2652
    float* yu_i  = yx_ei + INH_*EXC_;                // 26
    unsigned int* amax = (unsigned int*)(yu_i + INH_);   // 3
    // scatter partials overlay y_e (y_pre dead after smconv)
    float* parts_ee = y_e;                           // NPART*NEE
    float* parts_ie = parts_ee + (size_t)NPART*NEE;  // NPART*NIE

    // ---- 1: pack weights + x + zero atomic targets ----
    pack_all<<<3849, 256, 0, stream>>>(w_ee, w_ei, w_ie, x, wee, bigR, yx_ei);

    if (direct) {
        conv_mfma<96, 112, 7, EXC_, 3, false, false, true, 128, true>
            <<<dim3(16, 1, B_), 256, 0, stream>>>(bigR, wee, nullptr, y_e, yebf,
                                                  win_e, val_e);
        conv_mfma<128, 32, 2, INH_, 4, true, false, false, 32, true>
            <<<dim3(16, 1, B_), 256, 0, stream>>>(yebf, wei, nullptr, nullptr,
                                                  yibf, win_i, val_i);
        conv_mfma<32, 112, 7, EXC_, 1, false, true, true, 0, false>
            <<<dim3(16, 1, B_), 256, 0, stream>>>(yibf, wie, y_e, y_e, nullptr,
                                                  nullptr, nullptr);
    } else {
        conv_mfma<96, 112, 7, EXC_, 3, false, false, true, 0, true>
            <<<dim3(16, 1, B_), 256, 0, stream>>>(bigR, wee, nullptr, y_e, nullptr,
                                                  win_e, val_e);
        pack_nhwc<EXC_, 128><<<dim3(64, 1, B_), 256, 0, stream>>>(y_e, bigR);
        conv_mfma<128, 32, 2, INH_, 4, true, false, false, 32, true>
            <<<dim3(16, 1, B_), 256, 0, stream>>>(bigR, wei, nullptr, nullptr,
                                                  yibf, win_i, val_i);
        conv_mfma<32, 112, 7, EXC_, 1, false, true, true, 0, false>
            <<<dim3(16, 1, B_), 256, 0, stream>>>(yibf, wie, y_e, y_e, nullptr,
                                                  nullptr, nullptr);
    }

    // ---- 5: y = depthwise sm conv (zero pad) -> d_out chunk 0 ----
    smconv_v2<<<dim3(4, EXC_, B_), 256, 0, stream>>>(y_e, smk, out);

    // ---- 6-7: staged + position-permuted Hebbian scatters ----
    scatter_ee_kernel<<<NPART, 256, 0, stream>>>(x, win_e, val_e, parts_ee);
    scatter_iei_kernel<<<NPART, 256, 0, stream>>>(out, win_e, val_e, win_i,
                                                  val_i, yx_ei, yu_i, parts_ie);

    // ---- 8: fused reduce + absmax ----
    reduce_absmax_kernel<<<(NEE + NIE + NEI + 63)/64, 256, 0, stream>>>(
        parts_ee, parts_ie, yx_ei, yu_i, w_ee, w_ei, w_ie,
        yx_ee, yx_ie, amax);

    // ---- 9: upd write ----
    float* out_ee = out + (size_t)B_*EXC_*HW_;
    float* out_ei = out_ee + N1U;
    float* out_ie = out_ei + N2U;
    upd_write3<<<(N1U + N2U + N3U + 255)/256, 256, 0, stream>>>(
        yx_ee, yu_e, w_ee, yx_ei, yu_i, w_ei, yx_ie, w_ie, amax,
        out_ee, out_ei, out_ie);
}